// Round 2
// baseline (5265.107 us; speedup 1.0000x reference)
//
#include <hip/hip_runtime.h>
#include <hip/hip_bf16.h>

#define T_STEPS 64
#define B_DIM 2048
#define U_DIM 1024

#define BM 64          // batch rows per block
#define BU 64          // u-columns per block (each block does f-half AND c-half)
#define BK 32
#define LDS_STRIDE 40  // 32 + 8 halfs padding -> 2-way bank aliasing (free)
#define NBLOCKS (B_DIM / BM * (U_DIM / BU))   // 512

typedef __attribute__((ext_vector_type(8))) _Float16 h8;
typedef __attribute__((ext_vector_type(4))) float f4;

// ---------------- init kernels ----------------

// R: [U][2U] f32 row-major  ->  Rt: [2U][U] f16 (B^T layout for MFMA B-frags)
__global__ void transpose_R(const float* __restrict__ R, _Float16* __restrict__ Rt) {
    __shared__ float tile[32][33];
    int nb = blockIdx.x * 32;   // n block (2U dim)
    int kb = blockIdx.y * 32;   // k block (U dim)
    int tx = threadIdx.x, ty = threadIdx.y;   // block (32,8)
    #pragma unroll
    for (int i = ty; i < 32; i += 8)
        tile[i][tx] = R[(size_t)(kb + i) * (2 * U_DIM) + nb + tx];
    __syncthreads();
    #pragma unroll
    for (int i = ty; i < 32; i += 8)
        Rt[(size_t)(nb + i) * U_DIM + kb + tx] = (_Float16)tile[tx][i];
}

__global__ void init_state(const float* __restrict__ c0, _Float16* __restrict__ h0,
                           const float* __restrict__ x1_0, const float* __restrict__ x2_0,
                           float* __restrict__ x1w, float* __restrict__ x2w,
                           float* __restrict__ y, int* __restrict__ counter) {
    int i = blockIdx.x * 256 + threadIdx.x;
    h0[i] = (_Float16)c0[i];
    if (i < B_DIM) {
        x1w[i] = x1_0[i];
        x2w[i] = x2_0[i];
        y[i]   = 0.f;
    }
    if (i == 0) *counter = 0;
}

// ---------------- per-step fused GEMM + gates + tail-block integrator ----------------
__global__ __launch_bounds__(256, 2) void gemm_step(
    const _Float16* __restrict__ hA,   // [B][U] current h (f16)
    _Float16* __restrict__ hB,         // [B][U] next h  (f16)
    const _Float16* __restrict__ Rt,   // [2U][U]
    const float* __restrict__ x1w_c,   // [B] (read in epilogue)
    float* __restrict__ x1w,           // [B] (written by tail block)
    float* __restrict__ x2w,           // [B]
    const float* __restrict__ kern,    // [2U]
    const float* __restrict__ bias,    // [2U]
    const float* __restrict__ okern,   // [U]
    float* __restrict__ y,             // [B] partial output accum
    const float* __restrict__ inp_t,   // [B] this step's input row
    float* __restrict__ out_t,         // [B] this step's output row
    int* __restrict__ counter)
{
    __shared__ __align__(16) _Float16 lA [BM * LDS_STRIDE];
    __shared__ __align__(16) _Float16 lBf[BU * LDS_STRIDE];
    __shared__ __align__(16) _Float16 lBc[BU * LDS_STRIDE];
    __shared__ int s_is_last;

    const int tid    = threadIdx.x;
    const int wid    = tid >> 6;
    const int lane   = tid & 63;
    const int lane15 = lane & 15;
    const int quad   = lane >> 4;
    const int b0     = blockIdx.x * BM;
    const int u0     = blockIdx.y * BU;
    const int wrow   = (wid & 1) * 32;   // row offset within tile
    const int wcol   = (wid >> 1) * 32;  // u-col offset within tile

    f4 accF[2][2], accC[2][2];
    #pragma unroll
    for (int mt = 0; mt < 2; ++mt)
        #pragma unroll
        for (int nt = 0; nt < 2; ++nt) {
            accF[mt][nt] = (f4){0.f, 0.f, 0.f, 0.f};
            accC[mt][nt] = (f4){0.f, 0.f, 0.f, 0.f};
        }

    const int srow = tid >> 2;   // 0..63
    const int sch  = tid & 3;    // 16B chunk

    for (int kt = 0; kt < U_DIM / BK; ++kt) {
        const int k0 = kt * BK;
        // stage A (64x32 halfs), Bf, Bc (64x32 each) -- one uint4 per thread each
        const uint4 va = *(const uint4*)&hA[(size_t)(b0 + srow) * U_DIM + k0 + sch * 8];
        const uint4 vf = *(const uint4*)&Rt[(size_t)(u0 + srow) * U_DIM + k0 + sch * 8];
        const uint4 vc = *(const uint4*)&Rt[(size_t)(U_DIM + u0 + srow) * U_DIM + k0 + sch * 8];
        *(uint4*)&lA [srow * LDS_STRIDE + sch * 8] = va;
        *(uint4*)&lBf[srow * LDS_STRIDE + sch * 8] = vf;
        *(uint4*)&lBc[srow * LDS_STRIDE + sch * 8] = vc;
        __syncthreads();

        h8 af[2], bff[2], bfc[2];
        #pragma unroll
        for (int mt = 0; mt < 2; ++mt)
            af[mt] = *(const h8*)&lA[(wrow + mt * 16 + lane15) * LDS_STRIDE + quad * 8];
        #pragma unroll
        for (int nt = 0; nt < 2; ++nt) {
            bff[nt] = *(const h8*)&lBf[(wcol + nt * 16 + lane15) * LDS_STRIDE + quad * 8];
            bfc[nt] = *(const h8*)&lBc[(wcol + nt * 16 + lane15) * LDS_STRIDE + quad * 8];
        }
        #pragma unroll
        for (int mt = 0; mt < 2; ++mt)
            #pragma unroll
            for (int nt = 0; nt < 2; ++nt) {
                accF[mt][nt] = __builtin_amdgcn_mfma_f32_16x16x32_f16(af[mt], bff[nt], accF[mt][nt], 0, 0, 0);
                accC[mt][nt] = __builtin_amdgcn_mfma_f32_16x16x32_f16(af[mt], bfc[nt], accC[mt][nt], 0, 0, 0);
            }
        __syncthreads();
    }

    // ---- epilogue: gates, c write (f16), partial y via atomics ----
    #pragma unroll
    for (int mt = 0; mt < 2; ++mt) {
        const int b_base = b0 + wrow + mt * 16 + quad * 4;
        float psum[4] = {0.f, 0.f, 0.f, 0.f};
        #pragma unroll
        for (int nt = 0; nt < 2; ++nt) {
            const int u = u0 + wcol + nt * 16 + lane15;
            const float kf  = kern[u];
            const float kc  = kern[U_DIM + u];
            const float bfv = bias[u];
            const float bcv = bias[U_DIM + u];
            const float ok  = okern[u];
            #pragma unroll
            for (int reg = 0; reg < 4; ++reg) {
                const int b = b_base + reg;
                const float x1 = x1w_c[b];
                const float xf = accF[mt][nt][reg] + x1 * kf + bfv;
                const float xc = accC[mt][nt][reg] + x1 * kc + bcv;
                const float fg = 1.f / (1.f + __expf(-xf));
                const float th = 1.f - 2.f / (1.f + __expf(2.f * xc));
                const float hv = (float)hA[(size_t)b * U_DIM + u];
                const float cv = fg * hv + (1.f - fg) * th;
                hB[(size_t)b * U_DIM + u] = (_Float16)cv;
                psum[reg] += cv * ok;
            }
        }
        #pragma unroll
        for (int reg = 0; reg < 4; ++reg) {
            float s = psum[reg];
            s += __shfl_xor(s, 1);
            s += __shfl_xor(s, 2);
            s += __shfl_xor(s, 4);
            s += __shfl_xor(s, 8);
            if (lane15 == 0) atomicAdd(&y[b_base + reg], s);
        }
    }

    // ---- ticket: last block to finish does the integrator update ----
    __threadfence();
    __syncthreads();
    if (tid == 0) {
        int t = __hip_atomic_fetch_add(counter, 1, __ATOMIC_ACQ_REL, __HIP_MEMORY_SCOPE_AGENT);
        s_is_last = (t == NBLOCKS - 1) ? 1 : 0;
    }
    __syncthreads();
    if (s_is_last) {
        for (int b = tid; b < B_DIM; b += 256) {
            const float yv = __hip_atomic_load(&y[b], __ATOMIC_RELAXED, __HIP_MEMORY_SCOPE_AGENT);
            const float x1 = x1w[b];
            const float x2 = x2w[b];
            const float x1n = x1 + x2;
            const float x2n = x2 + inp_t[b] * yv;
            x1w[b] = x1n;
            x2w[b] = x2n;
            out_t[b] = x1n;
            __hip_atomic_store(&y[b], 0.f, __ATOMIC_RELAXED, __HIP_MEMORY_SCOPE_AGENT);
        }
        if (tid == 0)
            __hip_atomic_store(counter, 0, __ATOMIC_RELAXED, __HIP_MEMORY_SCOPE_AGENT);
    }
}

// ---------------- host ----------------
extern "C" void kernel_launch(void* const* d_in, const int* in_sizes, int n_in,
                              void* d_out, int out_size, void* d_ws, size_t ws_size,
                              hipStream_t stream) {
    const float* inputs = (const float*)d_in[0];   // T*B
    const float* x1_0   = (const float*)d_in[1];   // B
    const float* x2_0   = (const float*)d_in[2];   // B
    const float* c0     = (const float*)d_in[3];   // B*U
    const float* kern   = (const float*)d_in[4];   // 2U
    const float* rker   = (const float*)d_in[5];   // U*2U
    const float* bias   = (const float*)d_in[6];   // 2U
    const float* okern  = (const float*)d_in[7];   // U
    float* out = (float*)d_out;                    // T*B

    _Float16* Rt = (_Float16*)d_ws;                         // 2U*U halfs
    _Float16* h0 = Rt + (size_t)2 * U_DIM * U_DIM;
    _Float16* h1 = h0 + (size_t)B_DIM * U_DIM;
    float* x1w = (float*)(h1 + (size_t)B_DIM * U_DIM);
    float* x2w = x1w + B_DIM;
    float* y   = x2w + B_DIM;
    int* counter = (int*)(y + B_DIM);

    transpose_R<<<dim3(64, 32), dim3(32, 8), 0, stream>>>(rker, Rt);
    init_state<<<dim3(B_DIM * U_DIM / 256), dim3(256), 0, stream>>>(
        c0, h0, x1_0, x2_0, x1w, x2w, y, counter);

    _Float16* hcur = h0;
    _Float16* hnxt = h1;
    for (int t = 0; t < T_STEPS; ++t) {
        gemm_step<<<dim3(B_DIM / BM, U_DIM / BU), dim3(256), 0, stream>>>(
            hcur, hnxt, Rt, x1w, x1w, x2w, kern, bias, okern, y,
            inputs + (size_t)t * B_DIM, out + (size_t)t * B_DIM, counter);
        _Float16* tmp = hcur; hcur = hnxt; hnxt = tmp;
    }
}

// Round 3
// 2159.342 us; speedup vs baseline: 2.4383x; 2.4383x over previous
//
#include <hip/hip_runtime.h>
#include <hip/hip_bf16.h>

#define T_STEPS 64
#define B_DIM 2048
#define U_DIM 1024

#define BM 128
#define BU 64
#define BK 64
#define KITERS (U_DIM / BK)   // 16

typedef __attribute__((ext_vector_type(8))) _Float16 h8;
typedef __attribute__((ext_vector_type(4))) float f4;

// async global->LDS, 16B per lane; LDS dest = wave-uniform base + lane*16
__device__ __forceinline__ void async_cp16(const _Float16* g, _Float16* l) {
    __builtin_amdgcn_global_load_lds((const __attribute__((address_space(1))) void*)g,
                                     (__attribute__((address_space(3))) void*)l,
                                     16, 0, 0);
}

// ---------------- init kernels ----------------

// R: [U][2U] f32 row-major  ->  Rt: [2U][U] f16 (B^T layout for MFMA B-frags)
__global__ void transpose_R(const float* __restrict__ R, _Float16* __restrict__ Rt) {
    __shared__ float tile[32][33];
    int nb = blockIdx.x * 32;
    int kb = blockIdx.y * 32;
    int tx = threadIdx.x, ty = threadIdx.y;   // block (32,8)
    #pragma unroll
    for (int i = ty; i < 32; i += 8)
        tile[i][tx] = R[(size_t)(kb + i) * (2 * U_DIM) + nb + tx];
    __syncthreads();
    #pragma unroll
    for (int i = ty; i < 32; i += 8)
        Rt[(size_t)(nb + i) * U_DIM + kb + tx] = (_Float16)tile[tx][i];
}

__global__ void init_state(const float* __restrict__ c0, _Float16* __restrict__ h0,
                           const float* __restrict__ x1_0, const float* __restrict__ x2_0,
                           float* __restrict__ x1w, float* __restrict__ x2w,
                           float* __restrict__ y) {
    int i = blockIdx.x * 256 + threadIdx.x;
    h0[i] = (_Float16)c0[i];
    if (i < B_DIM) {
        x1w[i] = x1_0[i];
        x2w[i] = x2_0[i];
        y[i]   = 0.f;
    }
}

// ---------------- per-step fused GEMM + gates ----------------
// Tile (b0..b0+127, u0..u0+63), both f- and c-halves.
// Async double-buffered staging via global_load_lds; XOR-swizzled LDS chunks.
__global__ __launch_bounds__(256) void gemm_step(
    const _Float16* __restrict__ hA,   // [B][U] current h (f16)
    _Float16* __restrict__ hB,         // [B][U] next h  (f16)
    const _Float16* __restrict__ Rt,   // [2U][U]
    const float* __restrict__ x1w,     // [B]
    const float* __restrict__ kern,    // [2U]
    const float* __restrict__ bias,    // [2U]
    const float* __restrict__ okern,   // [U]
    float* __restrict__ y)             // [B] partial output accum
{
    __shared__ __align__(16) _Float16 lA [2][BM * BK];   // 2 x 16 KB
    __shared__ __align__(16) _Float16 lBf[2][BU * BK];   // 2 x  8 KB
    __shared__ __align__(16) _Float16 lBc[2][BU * BK];   // 2 x  8 KB

    const int tid    = threadIdx.x;
    const int wid    = tid >> 6;
    const int lane   = tid & 63;
    const int lane15 = lane & 15;
    const int quad   = lane >> 4;
    const int u0     = blockIdx.x * BU;   // u fast dim -> same-u blocks share XCD
    const int b0     = blockIdx.y * BM;
    const int wrow   = (wid >> 1) * 64;
    const int wcol   = (wid & 1) * 32;

    // staging lane mapping within a 64-chunk (1024B) region:
    // LDS chunk c = r*64 + lane; row = r*8 + (lane>>3); kchunk = (lane&7)^(lane>>3)
    const int srow8 = lane >> 3;
    const int skc   = (lane & 7) ^ srow8;

    f4 accF[4][2], accC[4][2];
    #pragma unroll
    for (int mt = 0; mt < 4; ++mt)
        #pragma unroll
        for (int nt = 0; nt < 2; ++nt) {
            accF[mt][nt] = (f4){0.f, 0.f, 0.f, 0.f};
            accC[mt][nt] = (f4){0.f, 0.f, 0.f, 0.f};
        }

    const _Float16* gA0  = hA + (size_t)(b0 + srow8) * U_DIM + skc * 8;
    const _Float16* gBf0 = Rt + (size_t)(u0 + srow8) * U_DIM + skc * 8;
    const _Float16* gBc0 = Rt + (size_t)(U_DIM + u0 + srow8) * U_DIM + skc * 8;

    auto stage = [&](int buf, int kt) {
        const int k0 = kt * BK;
        #pragma unroll
        for (int j = 0; j < 4; ++j) {              // A: 16 regions, 4 per wave
            const int r = wid * 4 + j;
            async_cp16(gA0 + (size_t)r * 8 * U_DIM + k0, &lA[buf][r * 512]);
        }
        #pragma unroll
        for (int j = 0; j < 2; ++j) {              // Bf/Bc: 8 regions, 2 per wave
            const int r = wid * 2 + j;
            async_cp16(gBf0 + (size_t)r * 8 * U_DIM + k0, &lBf[buf][r * 512]);
            async_cp16(gBc0 + (size_t)r * 8 * U_DIM + k0, &lBc[buf][r * 512]);
        }
    };

    stage(0, 0);

    const int axor = lane15 & 7;

    for (int kt = 0; kt < KITERS; ++kt) {
        const int cur = kt & 1;
        __builtin_amdgcn_s_waitcnt(0x0F70);   // vmcnt(0): own DMAs done
        __syncthreads();                      // everyone's DMAs done; prev reads done
        if (kt + 1 < KITERS) stage(1 - cur, kt + 1);   // overlaps compute below

        #pragma unroll
        for (int ks = 0; ks < 2; ++ks) {
            h8 af[4], bff[2], bfc[2];
            #pragma unroll
            for (int mt = 0; mt < 4; ++mt) {
                const int row = wrow + mt * 16 + lane15;
                const int kq  = ks * 4 + quad;
                af[mt] = *(const h8*)&lA[cur][(row * 8 + (kq ^ axor)) * 8];
            }
            #pragma unroll
            for (int nt = 0; nt < 2; ++nt) {
                const int row = wcol + nt * 16 + lane15;
                const int kq  = ks * 4 + quad;
                bff[nt] = *(const h8*)&lBf[cur][(row * 8 + (kq ^ axor)) * 8];
                bfc[nt] = *(const h8*)&lBc[cur][(row * 8 + (kq ^ axor)) * 8];
            }
            #pragma unroll
            for (int mt = 0; mt < 4; ++mt)
                #pragma unroll
                for (int nt = 0; nt < 2; ++nt) {
                    accF[mt][nt] = __builtin_amdgcn_mfma_f32_16x16x32_f16(af[mt], bff[nt], accF[mt][nt], 0, 0, 0);
                    accC[mt][nt] = __builtin_amdgcn_mfma_f32_16x16x32_f16(af[mt], bfc[nt], accC[mt][nt], 0, 0, 0);
                }
        }
    }

    // ---- epilogue: gates, c write (f16), partial y via plain atomics ----
    #pragma unroll
    for (int mt = 0; mt < 4; ++mt) {
        const int b_base = b0 + wrow + mt * 16 + quad * 4;
        float psum[4] = {0.f, 0.f, 0.f, 0.f};
        #pragma unroll
        for (int nt = 0; nt < 2; ++nt) {
            const int u = u0 + wcol + nt * 16 + lane15;
            const float kf  = kern[u];
            const float kc  = kern[U_DIM + u];
            const float bfv = bias[u];
            const float bcv = bias[U_DIM + u];
            const float ok  = okern[u];
            #pragma unroll
            for (int reg = 0; reg < 4; ++reg) {
                const int b = b_base + reg;
                const float x1 = x1w[b];
                const float xf = accF[mt][nt][reg] + x1 * kf + bfv;
                const float xc = accC[mt][nt][reg] + x1 * kc + bcv;
                const float fg = 1.f / (1.f + __expf(-xf));
                const float th = 1.f - 2.f / (1.f + __expf(2.f * xc));
                const float hv = (float)hA[(size_t)b * U_DIM + u];
                const float cv = fg * hv + (1.f - fg) * th;
                hB[(size_t)b * U_DIM + u] = (_Float16)cv;
                psum[reg] += cv * ok;
            }
        }
        #pragma unroll
        for (int reg = 0; reg < 4; ++reg) {
            float s = psum[reg];
            s += __shfl_xor(s, 1);
            s += __shfl_xor(s, 2);
            s += __shfl_xor(s, 4);
            s += __shfl_xor(s, 8);
            if (lane15 == 0) atomicAdd(&y[b_base + reg], s);
        }
    }
}

// ---------------- per-step state update ----------------
__global__ void step_update(const float* __restrict__ inp_t,
                            float* __restrict__ x1w, float* __restrict__ x2w,
                            float* __restrict__ y, float* __restrict__ out_t) {
    const int b = blockIdx.x * 256 + threadIdx.x;
    const float x1 = x1w[b];
    const float x2 = x2w[b];
    const float yv = y[b];
    const float x1n = x1 + x2;
    const float x2n = x2 + inp_t[b] * yv;
    x1w[b] = x1n;
    x2w[b] = x2n;
    out_t[b] = x1n;
    y[b] = 0.f;
}

// ---------------- host ----------------
extern "C" void kernel_launch(void* const* d_in, const int* in_sizes, int n_in,
                              void* d_out, int out_size, void* d_ws, size_t ws_size,
                              hipStream_t stream) {
    const float* inputs = (const float*)d_in[0];   // T*B
    const float* x1_0   = (const float*)d_in[1];   // B
    const float* x2_0   = (const float*)d_in[2];   // B
    const float* c0     = (const float*)d_in[3];   // B*U
    const float* kern   = (const float*)d_in[4];   // 2U
    const float* rker   = (const float*)d_in[5];   // U*2U
    const float* bias   = (const float*)d_in[6];   // 2U
    const float* okern  = (const float*)d_in[7];   // U
    float* out = (float*)d_out;                    // T*B

    _Float16* Rt = (_Float16*)d_ws;
    _Float16* h0 = Rt + (size_t)2 * U_DIM * U_DIM;
    _Float16* h1 = h0 + (size_t)B_DIM * U_DIM;
    float* x1w = (float*)(h1 + (size_t)B_DIM * U_DIM);
    float* x2w = x1w + B_DIM;
    float* y   = x2w + B_DIM;

    transpose_R<<<dim3(64, 32), dim3(32, 8), 0, stream>>>(rker, Rt);
    init_state<<<dim3(B_DIM * U_DIM / 256), dim3(256), 0, stream>>>(
        c0, h0, x1_0, x2_0, x1w, x2w, y);

    _Float16* hcur = h0;
    _Float16* hnxt = h1;
    for (int t = 0; t < T_STEPS; ++t) {
        gemm_step<<<dim3(U_DIM / BU, B_DIM / BM), dim3(256), 0, stream>>>(
            hcur, hnxt, Rt, x1w, kern, bias, okern, y);
        step_update<<<dim3(B_DIM / 256), dim3(256), 0, stream>>>(
            inputs + (size_t)t * B_DIM, x1w, x2w, y, out + (size_t)t * B_DIM);
        _Float16* tmp = hcur; hcur = hnxt; hnxt = tmp;
    }
}